// Round 8
// baseline (506.012 us; speedup 1.0000x reference)
//
#include <hip/hip_runtime.h>

typedef unsigned short u16;
typedef __attribute__((ext_vector_type(8))) short short8;
typedef __attribute__((ext_vector_type(4))) float f32x4;
typedef __attribute__((ext_vector_type(4))) unsigned short u16x4;

// ---------- bf16 helpers (OCP bf16 = raw upper 16 bits of fp32, RNE) ----------
__device__ __forceinline__ float bf2f(u16 h){
  unsigned u = ((unsigned)h) << 16; float f; __builtin_memcpy(&f, &u, 4); return f;
}
__device__ __forceinline__ u16 f2bf(float f){
  unsigned u; __builtin_memcpy(&u, &f, 4);
  unsigned r = u + 0x7fffu + ((u >> 16) & 1u);
  return (u16)(r >> 16);
}

// ---------- async global->LDS (16B per lane, wave-uniform LDS base) ----------
__device__ __forceinline__ void glds16(const u16* g, u16* l){
  __builtin_amdgcn_global_load_lds(
      (const __attribute__((address_space(1))) unsigned int*)(const void*)g,
      (__attribute__((address_space(3))) unsigned int*)(void*)l, 16, 0, 0);
}

// ---------- fused fp32 -> bf16 conversion: x (8192 blocks) + 4 weights ----------
__global__ __launch_bounds__(256) void cvt_all(const float* __restrict__ x,
    const float* __restrict__ w0, const float* __restrict__ w1,
    const float* __restrict__ w2, const float* __restrict__ w3,
    u16* __restrict__ xb, u16* __restrict__ wb){
  int blk = blockIdx.x;
  const float* src; u16* dst; int i;
  if (blk < 8192){
    src = x; dst = xb; i = blk * 256 + threadIdx.x;
  } else {
    int b2 = blk - 8192;
    int which = b2 >> 12;
    src = (which == 0) ? w0 : (which == 1) ? w1 : (which == 2) ? w2 : w3;
    dst = wb + (size_t)which * 4194304;
    i = (b2 & 4095) * 256 + threadIdx.x;
  }
  float4 f = ((const float4*)src)[i];
  u16x4 o; o.x = f2bf(f.x); o.y = f2bf(f.y); o.z = f2bf(f.z); o.w = f2bf(f.w);
  ((u16x4*)dst)[i] = o;
}

// ---------- GEMM C[M,N] = A[M,K] @ B[N,K]^T  (both bf16, K=2048, BK=64) ----------
// BK=64, register-dieted under the 128-VGPR cliff (compiled: 64 VGPR, ~1000 TF,
// MfmaUtil 45% -- at/above the 2-barrier structure ceiling). Unchanged.
__global__ __launch_bounds__(256, 4) void gemm_bt(
    const u16* __restrict__ A, const u16* __restrict__ Bm, int mode,
    u16* __restrict__ qws, u16* __restrict__ kws, u16* __restrict__ vws,
    const float* __restrict__ bq, const float* __restrict__ bk, const float* __restrict__ bv,
    float* __restrict__ outf, const float* __restrict__ bo)
{
  const int K = 2048;
  __shared__ __attribute__((aligned(16))) u16 As[128 * 64];   // 16 KB
  __shared__ __attribute__((aligned(16))) u16 Bs[128 * 64];   // 16 KB

  int tid = threadIdx.x, wave = tid >> 6, lane = tid & 63;
  int quad = lane >> 4, l15 = lane & 15;
  int wm = wave >> 1, wn = wave & 1;

  size_t rowA0 = (size_t)blockIdx.y * 128;
  size_t rowB0 = (size_t)blockIdx.x * 128;

  int lrow0 = tid >> 3;
  int c0 = (tid & 7) ^ (lrow0 & 7);
  const u16* gA = A  + (rowA0 + lrow0) * K + c0 * 8;
  const u16* gB = Bm + (rowB0 + lrow0) * K + c0 * 8;
  u16* lA = As + (size_t)(wave * 64) * 8;
  u16* lB = Bs + (size_t)(wave * 64) * 8;

  f32x4 acc[4][4];
  #pragma unroll
  for (int i = 0; i < 4; i++)
    #pragma unroll
    for (int j = 0; j < 4; j++) acc[i][j] = f32x4{0.f, 0.f, 0.f, 0.f};

  int aoff[4], boff[4];
  #pragma unroll
  for (int t = 0; t < 4; t++){
    int ra = wm * 64 + t * 16 + l15;
    aoff[t] = ra * 64 + ((quad ^ (ra & 7)) * 8);
    int rb = wn * 32 + (t >> 1) * 64 + (t & 1) * 16 + l15;
    boff[t] = rb * 64 + ((quad ^ (rb & 7)) * 8);
  }

  for (int k0 = 0; k0 < K; k0 += 64){
    __syncthreads();
    #pragma unroll
    for (int ri = 0; ri < 4; ri++){
      glds16(gA + ri * 65536, lA + ri * 2048);   // ri*32 rows * K elements
      glds16(gB + ri * 65536, lB + ri * 2048);
    }
    gA += 64; gB += 64;
    __syncthreads();
    #pragma unroll
    for (int kk = 0; kk < 2; kk++){
      const int kx = kk * 32;
      short8 af[4], bfr[4];
      #pragma unroll
      for (int t = 0; t < 4; t++){
        af[t]  = *(const short8*)(As + (aoff[t] ^ kx));
        bfr[t] = *(const short8*)(Bs + (boff[t] ^ kx));
      }
      #pragma unroll
      for (int i = 0; i < 4; i++)
        #pragma unroll
        for (int j = 0; j < 4; j++)
          acc[i][j] = __builtin_amdgcn_mfma_f32_16x16x32_bf16(af[i], bfr[j], acc[i][j], 0, 0, 0);
    }
  }

  if (mode == 0){
    int col0 = (int)rowB0;
    int mat = col0 >> 11;                  // 0=Q 1=K 2=V
    int cm  = col0 & 2047;
    const float* bias = (mat == 0) ? bq : (mat == 1) ? bk : bv;
    int b  = (int)(rowA0 >> 11);
    int s0 = (int)(rowA0 & 2047);
    int h  = cm >> 7;
    size_t base = ((size_t)(b * 16 + h)) * 2048 * 128;
    if (mat == 2){
      // V stored TRANSPOSED: [B,H,DK,S]
      #pragma unroll
      for (int j = 0; j < 4; j++){
        int d = wn * 32 + (j >> 1) * 64 + (j & 1) * 16 + l15;
        float bv_ = bias[cm + d];
        #pragma unroll
        for (int i = 0; i < 4; i++){
          int srow = s0 + wm * 64 + i * 16 + quad * 4;
          u16x4 pk;
          #pragma unroll
          for (int r = 0; r < 4; r++) pk[r] = f2bf(acc[i][j][r] + bv_);
          *(u16x4*)(vws + base + (size_t)d * 2048 + srow) = pk;
        }
      }
    } else {
      // Q/K: fused bias + RoPE
      u16* dst = (mat == 0) ? qws : kws;
      #pragma unroll
      for (int jp = 0; jp < 2; jp++){
        int dlow = wn * 32 + jp * 16 + l15;          // 0..63
        float bias_lo = bias[cm + dlow];
        float bias_hi = bias[cm + dlow + 64];
        float invf = __expf(-0.14391156831212788f * (float)dlow);
        #pragma unroll
        for (int i = 0; i < 4; i++){
          int srow0 = s0 + wm * 64 + i * 16 + quad * 4;
          #pragma unroll
          for (int r = 0; r < 4; r++){
            float a  = acc[i][jp][r]     + bias_lo;
            float b2 = acc[i][jp + 2][r] + bias_hi;
            float th = (float)(srow0 + r) * invf;
            float sn, cs; __sincosf(th, &sn, &cs);
            size_t ro = base + (size_t)(srow0 + r) * 128;
            dst[ro + dlow]      = f2bf(a * cs - b2 * sn);
            dst[ro + dlow + 64] = f2bf(b2 * cs + a * sn);
          }
        }
      }
    }
  } else {
    int col0 = (int)rowB0;
    #pragma unroll
    for (int j = 0; j < 4; j++){
      int c = col0 + wn * 32 + (j >> 1) * 64 + (j & 1) * 16 + l15;
      float bo_ = bo[c];
      #pragma unroll
      for (int i = 0; i < 4; i++){
        int rg = (int)rowA0 + wm * 64 + i * 16 + quad * 4;
        #pragma unroll
        for (int r = 0; r < 4; r++)
          outf[(size_t)(rg + r) * 2048 + c] = acc[i][j][r] + bo_;
      }
    }
  }
}

// ---------- causal flash attention v7: round-6 base + V-direct -> 4 blocks/CU ----
// Round-7 kv-split reverted (LDS=80K x2 = exactly 160K did NOT co-schedule ->
// 1 block/CU, 190 us; lesson: LDS must be strictly under pool/target-blocks).
// This round keeps round-6's simple 4-wave structure and takes only the verified
// ingredient: V read DIRECT from global (XCD-local L2; r7 proved correctness,
// FETCH stayed 24.6 MB). Deleting Vs halves LDS: 32K (K dbuf) + 8K (P) = 40 KB
// -> 4 blocks/CU = 16 waves/CU = 4 waves/SIMD of INDEPENDENT blocks (round 6
// had 2). launch_bounds(256,4): VGPR cap 128, flash live set ~110 fits.
// Lazy softmax (defer-max via lane-local __all; lane-partial lrp reduced once
// per phase) and zero-conflict P swizzle kept from round 6.
__global__ __launch_bounds__(256, 4) void flash(
    const u16* __restrict__ Q, const u16* __restrict__ Km, const u16* __restrict__ VT,
    u16* __restrict__ O)
{
  __shared__ __attribute__((aligned(16))) u16 Ks[2][64 * 128];  // 2x16 KB
  __shared__ __attribute__((aligned(16))) u16 PL[4 * 16 * 64];  // 8 KB per-wave P
  const float scale = 0.08838834764831845f;   // 1/sqrt(128)

  // XCD-chunked swizzle (id%8 -> XCD, measured r4: FETCH 254->24.6 MB).
  int id = (int)(blockIdx.x + (blockIdx.y << 4));
  int xcd = id & 7;
  int kk_ = id >> 3;                     // 0..63
  int bh = xcd + ((kk_ >> 4) << 3);      // {xcd, xcd+8, xcd+16, xcd+24}
  int pr = kk_ & 15;                     // 0..15
  int tid = threadIdx.x, wave = tid >> 6, lane = tid & 63;
  int quad = lane >> 4, l15 = lane & 15;

  const u16* Qb = Q  + (size_t)bh * 2048 * 128;
  const u16* Kb = Km + (size_t)bh * 2048 * 128;
  const u16* Vb = VT + (size_t)bh * 2048 * 128;   // [d=128][s=2048]
  u16* PW = PL + wave * (16 * 64);

  int krow0 = tid >> 4;
  const u16* gK0 = Kb + (size_t)krow0 * 128 + ((tid & 15) ^ (krow0 & 15)) * 8;
  int lOff0 = wave * 512;

  for (int phase = 0; phase < 2; phase++){
    int qtile = phase ? (31 - pr) : pr;
    int qw = qtile * 64 + wave * 16;

    short8 qf[4];
    {
      const u16* qr = Qb + (size_t)(qw + l15) * 128 + quad * 8;
      #pragma unroll
      for (int c = 0; c < 4; c++) qf[c] = *(const short8*)(qr + c * 32);
    }

    float mr[4], lrp[4]; f32x4 o[8];
    #pragma unroll
    for (int r = 0; r < 4; r++){ mr[r] = -1e30f; lrp[r] = 0.f; }
    #pragma unroll
    for (int blk = 0; blk < 8; blk++) o[blk] = f32x4{0.f, 0.f, 0.f, 0.f};

    int niter = qtile + 1;

    __syncthreads();   // previous phase's reads of Ks complete before re-staging
    #pragma unroll
    for (int r = 0; r < 4; r++)
      glds16(gK0 + r * 2048, Ks[0] + lOff0 + r * 2048);

    for (int it = 0; it < niter; it++){
      int k0 = it * 64;
      int buf = it & 1;
      __syncthreads();   // vmcnt(0)+barrier: buf's K tile landed; all waves done w/ buf^1
      if (it + 1 < niter){
        int nb = buf ^ 1;
        #pragma unroll
        for (int r = 0; r < 4; r++)
          glds16(gK0 + (size_t)(k0 + 64) * 128 + r * 2048, Ks[nb] + lOff0 + r * 2048);
      }
      const u16* KsB = Ks[buf];

      int rel = qw + 15 - k0;
      int smax = rel >> 4; if (smax > 3) smax = 3;
      float sreg[4][4];
      #pragma unroll
      for (int t = 0; t < 4; t++){
        if (t <= smax){
          short8 kf[4];
          #pragma unroll
          for (int c = 0; c < 4; c++)
            kf[c] = *(const short8*)(KsB + (t * 16 + l15) * 128 + (((c * 4 + quad) ^ l15) * 8));
          f32x4 a0 = f32x4{0.f, 0.f, 0.f, 0.f};
          f32x4 a1 = f32x4{0.f, 0.f, 0.f, 0.f};
          a0 = __builtin_amdgcn_mfma_f32_16x16x32_bf16(qf[0], kf[0], a0, 0, 0, 0);
          a1 = __builtin_amdgcn_mfma_f32_16x16x32_bf16(qf[1], kf[1], a1, 0, 0, 0);
          a0 = __builtin_amdgcn_mfma_f32_16x16x32_bf16(qf[2], kf[2], a0, 0, 0, 0);
          a1 = __builtin_amdgcn_mfma_f32_16x16x32_bf16(qf[3], kf[3], a1, 0, 0, 0);
          f32x4 a = a0 + a1;
          int kvcol = k0 + t * 16 + l15;
          #pragma unroll
          for (int r = 0; r < 4; r++){
            float v = a[r] * scale;
            int row = qw + quad * 4 + r;
            if (kvcol > row) v = -1e30f;
            sreg[t][r] = v;
          }
        }
      }
      // lane-local per-row tile max (no cross-lane reduce on the common path)
      float lm[4];
      #pragma unroll
      for (int r = 0; r < 4; r++){
        float x = sreg[0][r];
        #pragma unroll
        for (int t = 1; t < 4; t++) if (t <= smax) x = fmaxf(x, sreg[t][r]);
        lm[r] = x;
      }
      // defer-max (T13): single __all over all lanes covers every 16-lane row group
      float g01 = fmaxf(lm[0] - mr[0], lm[1] - mr[1]);
      float g23 = fmaxf(lm[2] - mr[2], lm[3] - mr[3]);
      int noresc = __all(fmaxf(g01, g23) <= 8.0f);
      if (!noresc){
        // rare path: full row-max reduce, rescale o and lane-partial lrp
        float alpha[4];
        #pragma unroll
        for (int r = 0; r < 4; r++){
          float x = lm[r];
          x = fmaxf(x, __shfl_xor(x, 1));
          x = fmaxf(x, __shfl_xor(x, 2));
          x = fmaxf(x, __shfl_xor(x, 4));
          x = fmaxf(x, __shfl_xor(x, 8));
          float mn = fmaxf(mr[r], x);
          alpha[r] = __expf(mr[r] - mn);
          mr[r] = mn;
        }
        #pragma unroll
        for (int r = 0; r < 4; r++) lrp[r] *= alpha[r];
        #pragma unroll
        for (int blk = 0; blk < 8; blk++){
          o[blk][0] *= alpha[0]; o[blk][1] *= alpha[1];
          o[blk][2] *= alpha[2]; o[blk][3] *= alpha[3];
        }
      }
      #pragma unroll
      for (int t = 0; t < 4; t++){
        if (t <= smax){
          int chi = t * 2 + (l15 >> 3);
          #pragma unroll
          for (int r = 0; r < 4; r++){
            float p = __expf(sreg[t][r] - mr[r]);
            lrp[r] += p;
            int row = quad * 4 + r;
            PW[row * 64 + ((chi ^ (row & 7)) << 3) + (l15 & 7)] = f2bf(p);
          }
        }
      }
      if (!(smax & 1)){
        int chi = (smax + 1) * 2 + (l15 >> 3);
        #pragma unroll
        for (int r = 0; r < 4; r++){
          int row = quad * 4 + r;
          PW[row * 64 + ((chi ^ (row & 7)) << 3) + (l15 & 7)] = 0;
        }
      }
      __builtin_amdgcn_s_waitcnt(0xC07F);   // lgkmcnt(0): own-wave P writes visible
      int nch = (smax >> 1) + 1;
      #pragma unroll
      for (int c2 = 0; c2 < 2; c2++){
        if (c2 < nch){
          short8 pf = *(const short8*)(PW + l15 * 64 + (((c2 * 4 + quad) ^ (l15 & 7)) << 3));
          const u16* vbase = Vb + k0 + c2 * 32 + quad * 8;   // direct (XCD-local L2)
          #pragma unroll
          for (int blk = 0; blk < 8; blk++){
            short8 vf = *(const short8*)(vbase + (size_t)(blk * 16 + l15) * 2048);
            o[blk] = __builtin_amdgcn_mfma_f32_16x16x32_bf16(pf, vf, o[blk], 0, 0, 0);
          }
        }
      }
    }

    // phase epilogue: ONE lane-group reduce of the lane-partial denominators
    int b = bh >> 4, h = bh & 15;
    float inv[4];
    #pragma unroll
    for (int r = 0; r < 4; r++){
      float sv = lrp[r];
      sv += __shfl_xor(sv, 1); sv += __shfl_xor(sv, 2);
      sv += __shfl_xor(sv, 4); sv += __shfl_xor(sv, 8);
      inv[r] = 1.0f / sv;
    }
    #pragma unroll
    for (int blk = 0; blk < 8; blk++){
      int d = h * 128 + blk * 16 + l15;
      #pragma unroll
      for (int r = 0; r < 4; r++){
        int srow = qw + quad * 4 + r;
        O[((size_t)(b * 2048 + srow)) * 2048 + d] = f2bf(o[blk][r] * inv[r]);
      }
    }
  }
}

// ---------- launcher ----------
extern "C" void kernel_launch(void* const* d_in, const int* in_sizes, int n_in,
                              void* d_out, int out_size, void* d_ws, size_t ws_size,
                              hipStream_t stream)
{
  const float* x  = (const float*)d_in[0];
  const float* Wq = (const float*)d_in[2];
  const float* bq = (const float*)d_in[3];
  const float* Wk = (const float*)d_in[4];
  const float* bk = (const float*)d_in[5];
  const float* Wv = (const float*)d_in[6];
  const float* bv = (const float*)d_in[7];
  const float* Wo = (const float*)d_in[8];
  const float* bo = (const float*)d_in[9];
  float* out = (float*)d_out;

  char* ws = (char*)d_ws;
  u16* xb   = (u16*)(ws);                    // [4096][2048]
  u16* wcat = (u16*)(ws + 16777216);         // [6144][2048] Wq|Wk|Wv
  u16* wob  = (u16*)(ws + 41943040);         // [2048][2048]
  u16* qws  = (u16*)(ws + 50331648);         // [32][2048][128]
  u16* kws  = (u16*)(ws + 67108864);
  u16* vws  = (u16*)(ws + 83886080);         // [32][128][2048] V^T
  u16* attn = (u16*)(ws + 100663296);        // [4096][2048]

  cvt_all<<<24576, 256, 0, stream>>>(x, Wq, Wk, Wv, Wo, xb, wcat);

  gemm_bt<<<dim3(48, 32), 256, 0, stream>>>(xb, wcat, 0, qws, kws, vws,
                                            bq, bk, bv, nullptr, nullptr);
  flash<<<dim3(16, 32), 256, 0, stream>>>(qws, kws, vws, attn);
  gemm_bt<<<dim3(16, 32), 256, 0, stream>>>(attn, wob, 1, nullptr, nullptr, nullptr,
                                            nullptr, nullptr, nullptr, out, bo);
}

// Round 9
// 481.069 us; speedup vs baseline: 1.0518x; 1.0518x over previous
//
#include <hip/hip_runtime.h>

typedef unsigned short u16;
typedef __attribute__((ext_vector_type(8))) short short8;
typedef __attribute__((ext_vector_type(4))) float f32x4;
typedef __attribute__((ext_vector_type(4))) unsigned short u16x4;

// ---------- bf16 helpers (OCP bf16 = raw upper 16 bits of fp32, RNE) ----------
__device__ __forceinline__ float bf2f(u16 h){
  unsigned u = ((unsigned)h) << 16; float f; __builtin_memcpy(&f, &u, 4); return f;
}
__device__ __forceinline__ u16 f2bf(float f){
  unsigned u; __builtin_memcpy(&u, &f, 4);
  unsigned r = u + 0x7fffu + ((u >> 16) & 1u);
  return (u16)(r >> 16);
}

// ---------- async global->LDS (16B per lane, wave-uniform LDS base) ----------
__device__ __forceinline__ void glds16(const u16* g, u16* l){
  __builtin_amdgcn_global_load_lds(
      (const __attribute__((address_space(1))) unsigned int*)(const void*)g,
      (__attribute__((address_space(3))) unsigned int*)(void*)l, 16, 0, 0);
}

// ---------- fused fp32 -> bf16 conversion: x (8192 blocks) + 4 weights ----------
__global__ __launch_bounds__(256) void cvt_all(const float* __restrict__ x,
    const float* __restrict__ w0, const float* __restrict__ w1,
    const float* __restrict__ w2, const float* __restrict__ w3,
    u16* __restrict__ xb, u16* __restrict__ wb){
  int blk = blockIdx.x;
  const float* src; u16* dst; int i;
  if (blk < 8192){
    src = x; dst = xb; i = blk * 256 + threadIdx.x;
  } else {
    int b2 = blk - 8192;
    int which = b2 >> 12;
    src = (which == 0) ? w0 : (which == 1) ? w1 : (which == 2) ? w2 : w3;
    dst = wb + (size_t)which * 4194304;
    i = (b2 & 4095) * 256 + threadIdx.x;
  }
  float4 f = ((const float4*)src)[i];
  u16x4 o; o.x = f2bf(f.x); o.y = f2bf(f.y); o.z = f2bf(f.z); o.w = f2bf(f.w);
  ((u16x4*)dst)[i] = o;
}

// ---------- GEMM C[M,N] = A[M,K] @ B[N,K]^T  (both bf16, K=2048, BK=64) ----------
// BK=64, register-dieted (compiled: 64 VGPR fits the (256,4) cap, ~1000 TF,
// MfmaUtil 45% -- at/above the 2-barrier structure ceiling). Unchanged.
__global__ __launch_bounds__(256, 4) void gemm_bt(
    const u16* __restrict__ A, const u16* __restrict__ Bm, int mode,
    u16* __restrict__ qws, u16* __restrict__ kws, u16* __restrict__ vws,
    const float* __restrict__ bq, const float* __restrict__ bk, const float* __restrict__ bv,
    float* __restrict__ outf, const float* __restrict__ bo)
{
  const int K = 2048;
  __shared__ __attribute__((aligned(16))) u16 As[128 * 64];   // 16 KB
  __shared__ __attribute__((aligned(16))) u16 Bs[128 * 64];   // 16 KB

  int tid = threadIdx.x, wave = tid >> 6, lane = tid & 63;
  int quad = lane >> 4, l15 = lane & 15;
  int wm = wave >> 1, wn = wave & 1;

  size_t rowA0 = (size_t)blockIdx.y * 128;
  size_t rowB0 = (size_t)blockIdx.x * 128;

  int lrow0 = tid >> 3;
  int c0 = (tid & 7) ^ (lrow0 & 7);
  const u16* gA = A  + (rowA0 + lrow0) * K + c0 * 8;
  const u16* gB = Bm + (rowB0 + lrow0) * K + c0 * 8;
  u16* lA = As + (size_t)(wave * 64) * 8;
  u16* lB = Bs + (size_t)(wave * 64) * 8;

  f32x4 acc[4][4];
  #pragma unroll
  for (int i = 0; i < 4; i++)
    #pragma unroll
    for (int j = 0; j < 4; j++) acc[i][j] = f32x4{0.f, 0.f, 0.f, 0.f};

  int aoff[4], boff[4];
  #pragma unroll
  for (int t = 0; t < 4; t++){
    int ra = wm * 64 + t * 16 + l15;
    aoff[t] = ra * 64 + ((quad ^ (ra & 7)) * 8);
    int rb = wn * 32 + (t >> 1) * 64 + (t & 1) * 16 + l15;
    boff[t] = rb * 64 + ((quad ^ (rb & 7)) * 8);
  }

  for (int k0 = 0; k0 < K; k0 += 64){
    __syncthreads();
    #pragma unroll
    for (int ri = 0; ri < 4; ri++){
      glds16(gA + ri * 65536, lA + ri * 2048);   // ri*32 rows * K elements
      glds16(gB + ri * 65536, lB + ri * 2048);
    }
    gA += 64; gB += 64;
    __syncthreads();
    #pragma unroll
    for (int kk = 0; kk < 2; kk++){
      const int kx = kk * 32;
      short8 af[4], bfr[4];
      #pragma unroll
      for (int t = 0; t < 4; t++){
        af[t]  = *(const short8*)(As + (aoff[t] ^ kx));
        bfr[t] = *(const short8*)(Bs + (boff[t] ^ kx));
      }
      #pragma unroll
      for (int i = 0; i < 4; i++)
        #pragma unroll
        for (int j = 0; j < 4; j++)
          acc[i][j] = __builtin_amdgcn_mfma_f32_16x16x32_bf16(af[i], bfr[j], acc[i][j], 0, 0, 0);
    }
  }

  if (mode == 0){
    int col0 = (int)rowB0;
    int mat = col0 >> 11;                  // 0=Q 1=K 2=V
    int cm  = col0 & 2047;
    const float* bias = (mat == 0) ? bq : (mat == 1) ? bk : bv;
    int b  = (int)(rowA0 >> 11);
    int s0 = (int)(rowA0 & 2047);
    int h  = cm >> 7;
    size_t base = ((size_t)(b * 16 + h)) * 2048 * 128;
    if (mat == 2){
      // V stored TRANSPOSED: [B,H,DK,S]
      #pragma unroll
      for (int j = 0; j < 4; j++){
        int d = wn * 32 + (j >> 1) * 64 + (j & 1) * 16 + l15;
        float bv_ = bias[cm + d];
        #pragma unroll
        for (int i = 0; i < 4; i++){
          int srow = s0 + wm * 64 + i * 16 + quad * 4;
          u16x4 pk;
          #pragma unroll
          for (int r = 0; r < 4; r++) pk[r] = f2bf(acc[i][j][r] + bv_);
          *(u16x4*)(vws + base + (size_t)d * 2048 + srow) = pk;
        }
      }
    } else {
      // Q/K: fused bias + RoPE
      u16* dst = (mat == 0) ? qws : kws;
      #pragma unroll
      for (int jp = 0; jp < 2; jp++){
        int dlow = wn * 32 + jp * 16 + l15;          // 0..63
        float bias_lo = bias[cm + dlow];
        float bias_hi = bias[cm + dlow + 64];
        float invf = __expf(-0.14391156831212788f * (float)dlow);
        #pragma unroll
        for (int i = 0; i < 4; i++){
          int srow0 = s0 + wm * 64 + i * 16 + quad * 4;
          #pragma unroll
          for (int r = 0; r < 4; r++){
            float a  = acc[i][jp][r]     + bias_lo;
            float b2 = acc[i][jp + 2][r] + bias_hi;
            float th = (float)(srow0 + r) * invf;
            float sn, cs; __sincosf(th, &sn, &cs);
            size_t ro = base + (size_t)(srow0 + r) * 128;
            dst[ro + dlow]      = f2bf(a * cs - b2 * sn);
            dst[ro + dlow + 64] = f2bf(b2 * cs + a * sn);
          }
        }
      }
    }
  } else {
    int col0 = (int)rowB0;
    #pragma unroll
    for (int j = 0; j < 4; j++){
      int c = col0 + wn * 32 + (j >> 1) * 64 + (j & 1) * 16 + l15;
      float bo_ = bo[c];
      #pragma unroll
      for (int i = 0; i < 4; i++){
        int rg = (int)rowA0 + wm * 64 + i * 16 + quad * 4;
        #pragma unroll
        for (int r = 0; r < 4; r++)
          outf[(size_t)(rg + r) * 2048 + c] = acc[i][j][r] + bo_;
      }
    }
  }
}

// ---------- causal flash attention v8: V-direct, 40 KB LDS, VGPR cap FIXED ------
// One-variable change from round 8: __launch_bounds__(256, 2). Session-empirical
// cap model: cap ~ 256/min_waves_arg ((256,4) and (512,4) -> 64 = spills for
// flash's ~110 live set; (256,2)/(512,2) -> 96+ healthy). Round 8's V-direct
// structure kept: LDS = 32K K-dbuf + 8K P = 40 KB -> 3 blocks/CU (163840-B pool
// minus exact-fit rule), per-iter barrier drain is only 4 glds16 (Vs staging
// gone). Lazy softmax + zero-conflict P swizzle + XCD swizzle unchanged.
__global__ __launch_bounds__(256, 2) void flash(
    const u16* __restrict__ Q, const u16* __restrict__ Km, const u16* __restrict__ VT,
    u16* __restrict__ O)
{
  __shared__ __attribute__((aligned(16))) u16 Ks[2][64 * 128];  // 2x16 KB
  __shared__ __attribute__((aligned(16))) u16 PL[4 * 16 * 64];  // 8 KB per-wave P
  const float scale = 0.08838834764831845f;   // 1/sqrt(128)

  // XCD-chunked swizzle (id%8 -> XCD, measured r4: FETCH 254->24.6 MB).
  int id = (int)(blockIdx.x + (blockIdx.y << 4));
  int xcd = id & 7;
  int kk_ = id >> 3;                     // 0..63
  int bh = xcd + ((kk_ >> 4) << 3);      // {xcd, xcd+8, xcd+16, xcd+24}
  int pr = kk_ & 15;                     // 0..15
  int tid = threadIdx.x, wave = tid >> 6, lane = tid & 63;
  int quad = lane >> 4, l15 = lane & 15;

  const u16* Qb = Q  + (size_t)bh * 2048 * 128;
  const u16* Kb = Km + (size_t)bh * 2048 * 128;
  const u16* Vb = VT + (size_t)bh * 2048 * 128;   // [d=128][s=2048]
  u16* PW = PL + wave * (16 * 64);

  int krow0 = tid >> 4;
  const u16* gK0 = Kb + (size_t)krow0 * 128 + ((tid & 15) ^ (krow0 & 15)) * 8;
  int lOff0 = wave * 512;

  for (int phase = 0; phase < 2; phase++){
    int qtile = phase ? (31 - pr) : pr;
    int qw = qtile * 64 + wave * 16;

    short8 qf[4];
    {
      const u16* qr = Qb + (size_t)(qw + l15) * 128 + quad * 8;
      #pragma unroll
      for (int c = 0; c < 4; c++) qf[c] = *(const short8*)(qr + c * 32);
    }

    float mr[4], lrp[4]; f32x4 o[8];
    #pragma unroll
    for (int r = 0; r < 4; r++){ mr[r] = -1e30f; lrp[r] = 0.f; }
    #pragma unroll
    for (int blk = 0; blk < 8; blk++) o[blk] = f32x4{0.f, 0.f, 0.f, 0.f};

    int niter = qtile + 1;

    __syncthreads();   // previous phase's reads of Ks complete before re-staging
    #pragma unroll
    for (int r = 0; r < 4; r++)
      glds16(gK0 + r * 2048, Ks[0] + lOff0 + r * 2048);

    for (int it = 0; it < niter; it++){
      int k0 = it * 64;
      int buf = it & 1;
      __syncthreads();   // vmcnt(0)+barrier: buf's K tile landed; all waves done w/ buf^1
      if (it + 1 < niter){
        int nb = buf ^ 1;
        #pragma unroll
        for (int r = 0; r < 4; r++)
          glds16(gK0 + (size_t)(k0 + 64) * 128 + r * 2048, Ks[nb] + lOff0 + r * 2048);
      }
      const u16* KsB = Ks[buf];

      int rel = qw + 15 - k0;
      int smax = rel >> 4; if (smax > 3) smax = 3;
      float sreg[4][4];
      #pragma unroll
      for (int t = 0; t < 4; t++){
        if (t <= smax){
          short8 kf[4];
          #pragma unroll
          for (int c = 0; c < 4; c++)
            kf[c] = *(const short8*)(KsB + (t * 16 + l15) * 128 + (((c * 4 + quad) ^ l15) * 8));
          f32x4 a0 = f32x4{0.f, 0.f, 0.f, 0.f};
          f32x4 a1 = f32x4{0.f, 0.f, 0.f, 0.f};
          a0 = __builtin_amdgcn_mfma_f32_16x16x32_bf16(qf[0], kf[0], a0, 0, 0, 0);
          a1 = __builtin_amdgcn_mfma_f32_16x16x32_bf16(qf[1], kf[1], a1, 0, 0, 0);
          a0 = __builtin_amdgcn_mfma_f32_16x16x32_bf16(qf[2], kf[2], a0, 0, 0, 0);
          a1 = __builtin_amdgcn_mfma_f32_16x16x32_bf16(qf[3], kf[3], a1, 0, 0, 0);
          f32x4 a = a0 + a1;
          int kvcol = k0 + t * 16 + l15;
          #pragma unroll
          for (int r = 0; r < 4; r++){
            float v = a[r] * scale;
            int row = qw + quad * 4 + r;
            if (kvcol > row) v = -1e30f;
            sreg[t][r] = v;
          }
        }
      }
      // lane-local per-row tile max (no cross-lane reduce on the common path)
      float lm[4];
      #pragma unroll
      for (int r = 0; r < 4; r++){
        float x = sreg[0][r];
        #pragma unroll
        for (int t = 1; t < 4; t++) if (t <= smax) x = fmaxf(x, sreg[t][r]);
        lm[r] = x;
      }
      // defer-max (T13): single __all over all lanes covers every 16-lane row group
      float g01 = fmaxf(lm[0] - mr[0], lm[1] - mr[1]);
      float g23 = fmaxf(lm[2] - mr[2], lm[3] - mr[3]);
      int noresc = __all(fmaxf(g01, g23) <= 8.0f);
      if (!noresc){
        // rare path: full row-max reduce, rescale o and lane-partial lrp
        float alpha[4];
        #pragma unroll
        for (int r = 0; r < 4; r++){
          float x = lm[r];
          x = fmaxf(x, __shfl_xor(x, 1));
          x = fmaxf(x, __shfl_xor(x, 2));
          x = fmaxf(x, __shfl_xor(x, 4));
          x = fmaxf(x, __shfl_xor(x, 8));
          float mn = fmaxf(mr[r], x);
          alpha[r] = __expf(mr[r] - mn);
          mr[r] = mn;
        }
        #pragma unroll
        for (int r = 0; r < 4; r++) lrp[r] *= alpha[r];
        #pragma unroll
        for (int blk = 0; blk < 8; blk++){
          o[blk][0] *= alpha[0]; o[blk][1] *= alpha[1];
          o[blk][2] *= alpha[2]; o[blk][3] *= alpha[3];
        }
      }
      #pragma unroll
      for (int t = 0; t < 4; t++){
        if (t <= smax){
          int chi = t * 2 + (l15 >> 3);
          #pragma unroll
          for (int r = 0; r < 4; r++){
            float p = __expf(sreg[t][r] - mr[r]);
            lrp[r] += p;
            int row = quad * 4 + r;
            PW[row * 64 + ((chi ^ (row & 7)) << 3) + (l15 & 7)] = f2bf(p);
          }
        }
      }
      if (!(smax & 1)){
        int chi = (smax + 1) * 2 + (l15 >> 3);
        #pragma unroll
        for (int r = 0; r < 4; r++){
          int row = quad * 4 + r;
          PW[row * 64 + ((chi ^ (row & 7)) << 3) + (l15 & 7)] = 0;
        }
      }
      __builtin_amdgcn_s_waitcnt(0xC07F);   // lgkmcnt(0): own-wave P writes visible
      int nch = (smax >> 1) + 1;
      #pragma unroll
      for (int c2 = 0; c2 < 2; c2++){
        if (c2 < nch){
          short8 pf = *(const short8*)(PW + l15 * 64 + (((c2 * 4 + quad) ^ (l15 & 7)) << 3));
          const u16* vbase = Vb + k0 + c2 * 32 + quad * 8;   // direct (XCD-local L2)
          #pragma unroll
          for (int blk = 0; blk < 8; blk++){
            short8 vf = *(const short8*)(vbase + (size_t)(blk * 16 + l15) * 2048);
            o[blk] = __builtin_amdgcn_mfma_f32_16x16x32_bf16(pf, vf, o[blk], 0, 0, 0);
          }
        }
      }
    }

    // phase epilogue: ONE lane-group reduce of the lane-partial denominators
    int b = bh >> 4, h = bh & 15;
    float inv[4];
    #pragma unroll
    for (int r = 0; r < 4; r++){
      float sv = lrp[r];
      sv += __shfl_xor(sv, 1); sv += __shfl_xor(sv, 2);
      sv += __shfl_xor(sv, 4); sv += __shfl_xor(sv, 8);
      inv[r] = 1.0f / sv;
    }
    #pragma unroll
    for (int blk = 0; blk < 8; blk++){
      int d = h * 128 + blk * 16 + l15;
      #pragma unroll
      for (int r = 0; r < 4; r++){
        int srow = qw + quad * 4 + r;
        O[((size_t)(b * 2048 + srow)) * 2048 + d] = f2bf(o[blk][r] * inv[r]);
      }
    }
  }
}

// ---------- launcher ----------
extern "C" void kernel_launch(void* const* d_in, const int* in_sizes, int n_in,
                              void* d_out, int out_size, void* d_ws, size_t ws_size,
                              hipStream_t stream)
{
  const float* x  = (const float*)d_in[0];
  const float* Wq = (const float*)d_in[2];
  const float* bq = (const float*)d_in[3];
  const float* Wk = (const float*)d_in[4];
  const float* bk = (const float*)d_in[5];
  const float* Wv = (const float*)d_in[6];
  const float* bv = (const float*)d_in[7];
  const float* Wo = (const float*)d_in[8];
  const float* bo = (const float*)d_in[9];
  float* out = (float*)d_out;

  char* ws = (char*)d_ws;
  u16* xb   = (u16*)(ws);                    // [4096][2048]
  u16* wcat = (u16*)(ws + 16777216);         // [6144][2048] Wq|Wk|Wv
  u16* wob  = (u16*)(ws + 41943040);         // [2048][2048]
  u16* qws  = (u16*)(ws + 50331648);         // [32][2048][128]
  u16* kws  = (u16*)(ws + 67108864);
  u16* vws  = (u16*)(ws + 83886080);         // [32][128][2048] V^T
  u16* attn = (u16*)(ws + 100663296);        // [4096][2048]

  cvt_all<<<24576, 256, 0, stream>>>(x, Wq, Wk, Wv, Wo, xb, wcat);

  gemm_bt<<<dim3(48, 32), 256, 0, stream>>>(xb, wcat, 0, qws, kws, vws,
                                            bq, bk, bv, nullptr, nullptr);
  flash<<<dim3(16, 32), 256, 0, stream>>>(qws, kws, vws, attn);
  gemm_bt<<<dim3(16, 32), 256, 0, stream>>>(attn, wob, 1, nullptr, nullptr, nullptr,
                                            nullptr, nullptr, nullptr, out, bo);
}

// Round 10
// 373.666 us; speedup vs baseline: 1.3542x; 1.2874x over previous
//
#include <hip/hip_runtime.h>

typedef unsigned short u16;
typedef __attribute__((ext_vector_type(8))) short short8;
typedef __attribute__((ext_vector_type(4))) float f32x4;
typedef __attribute__((ext_vector_type(4))) unsigned short u16x4;

// ---------- bf16 helpers (OCP bf16 = raw upper 16 bits of fp32, RNE) ----------
__device__ __forceinline__ float bf2f(u16 h){
  unsigned u = ((unsigned)h) << 16; float f; __builtin_memcpy(&f, &u, 4); return f;
}
__device__ __forceinline__ u16 f2bf(float f){
  unsigned u; __builtin_memcpy(&u, &f, 4);
  unsigned r = u + 0x7fffu + ((u >> 16) & 1u);
  return (u16)(r >> 16);
}

// ---------- async global->LDS (16B per lane, wave-uniform LDS base) ----------
__device__ __forceinline__ void glds16(const u16* g, u16* l){
  __builtin_amdgcn_global_load_lds(
      (const __attribute__((address_space(1))) unsigned int*)(const void*)g,
      (__attribute__((address_space(3))) unsigned int*)(void*)l, 16, 0, 0);
}

// ---------- fused fp32 -> bf16 conversion: x (8192 blocks) + 4 weights ----------
__global__ __launch_bounds__(256) void cvt_all(const float* __restrict__ x,
    const float* __restrict__ w0, const float* __restrict__ w1,
    const float* __restrict__ w2, const float* __restrict__ w3,
    u16* __restrict__ xb, u16* __restrict__ wb){
  int blk = blockIdx.x;
  const float* src; u16* dst; int i;
  if (blk < 8192){
    src = x; dst = xb; i = blk * 256 + threadIdx.x;
  } else {
    int b2 = blk - 8192;
    int which = b2 >> 12;
    src = (which == 0) ? w0 : (which == 1) ? w1 : (which == 2) ? w2 : w3;
    dst = wb + (size_t)which * 4194304;
    i = (b2 & 4095) * 256 + threadIdx.x;
  }
  float4 f = ((const float4*)src)[i];
  u16x4 o; o.x = f2bf(f.x); o.y = f2bf(f.y); o.z = f2bf(f.z); o.w = f2bf(f.w);
  ((u16x4*)dst)[i] = o;
}

// ---------- GEMM C[M,N] = A[M,K] @ B[N,K]^T  (both bf16, K=2048, BK=64) ----------
// BK=64, register-dieted (compiled: 64 VGPR, ~1000 TF, MfmaUtil 45% -- at/above
// the 2-barrier structure ceiling). Unchanged since round 6.
__global__ __launch_bounds__(256, 4) void gemm_bt(
    const u16* __restrict__ A, const u16* __restrict__ Bm, int mode,
    u16* __restrict__ qws, u16* __restrict__ kws, u16* __restrict__ vws,
    const float* __restrict__ bq, const float* __restrict__ bk, const float* __restrict__ bv,
    float* __restrict__ outf, const float* __restrict__ bo)
{
  const int K = 2048;
  __shared__ __attribute__((aligned(16))) u16 As[128 * 64];   // 16 KB
  __shared__ __attribute__((aligned(16))) u16 Bs[128 * 64];   // 16 KB

  int tid = threadIdx.x, wave = tid >> 6, lane = tid & 63;
  int quad = lane >> 4, l15 = lane & 15;
  int wm = wave >> 1, wn = wave & 1;

  size_t rowA0 = (size_t)blockIdx.y * 128;
  size_t rowB0 = (size_t)blockIdx.x * 128;

  int lrow0 = tid >> 3;
  int c0 = (tid & 7) ^ (lrow0 & 7);
  const u16* gA = A  + (rowA0 + lrow0) * K + c0 * 8;
  const u16* gB = Bm + (rowB0 + lrow0) * K + c0 * 8;
  u16* lA = As + (size_t)(wave * 64) * 8;
  u16* lB = Bs + (size_t)(wave * 64) * 8;

  f32x4 acc[4][4];
  #pragma unroll
  for (int i = 0; i < 4; i++)
    #pragma unroll
    for (int j = 0; j < 4; j++) acc[i][j] = f32x4{0.f, 0.f, 0.f, 0.f};

  int aoff[4], boff[4];
  #pragma unroll
  for (int t = 0; t < 4; t++){
    int ra = wm * 64 + t * 16 + l15;
    aoff[t] = ra * 64 + ((quad ^ (ra & 7)) * 8);
    int rb = wn * 32 + (t >> 1) * 64 + (t & 1) * 16 + l15;
    boff[t] = rb * 64 + ((quad ^ (rb & 7)) * 8);
  }

  for (int k0 = 0; k0 < K; k0 += 64){
    __syncthreads();
    #pragma unroll
    for (int ri = 0; ri < 4; ri++){
      glds16(gA + ri * 65536, lA + ri * 2048);   // ri*32 rows * K elements
      glds16(gB + ri * 65536, lB + ri * 2048);
    }
    gA += 64; gB += 64;
    __syncthreads();
    #pragma unroll
    for (int kk = 0; kk < 2; kk++){
      const int kx = kk * 32;
      short8 af[4], bfr[4];
      #pragma unroll
      for (int t = 0; t < 4; t++){
        af[t]  = *(const short8*)(As + (aoff[t] ^ kx));
        bfr[t] = *(const short8*)(Bs + (boff[t] ^ kx));
      }
      #pragma unroll
      for (int i = 0; i < 4; i++)
        #pragma unroll
        for (int j = 0; j < 4; j++)
          acc[i][j] = __builtin_amdgcn_mfma_f32_16x16x32_bf16(af[i], bfr[j], acc[i][j], 0, 0, 0);
    }
  }

  if (mode == 0){
    int col0 = (int)rowB0;
    int mat = col0 >> 11;                  // 0=Q 1=K 2=V
    int cm  = col0 & 2047;
    const float* bias = (mat == 0) ? bq : (mat == 1) ? bk : bv;
    int b  = (int)(rowA0 >> 11);
    int s0 = (int)(rowA0 & 2047);
    int h  = cm >> 7;
    size_t base = ((size_t)(b * 16 + h)) * 2048 * 128;
    if (mat == 2){
      // V stored TRANSPOSED: [B,H,DK,S]
      #pragma unroll
      for (int j = 0; j < 4; j++){
        int d = wn * 32 + (j >> 1) * 64 + (j & 1) * 16 + l15;
        float bv_ = bias[cm + d];
        #pragma unroll
        for (int i = 0; i < 4; i++){
          int srow = s0 + wm * 64 + i * 16 + quad * 4;
          u16x4 pk;
          #pragma unroll
          for (int r = 0; r < 4; r++) pk[r] = f2bf(acc[i][j][r] + bv_);
          *(u16x4*)(vws + base + (size_t)d * 2048 + srow) = pk;
        }
      }
    } else {
      // Q/K: fused bias + RoPE
      u16* dst = (mat == 0) ? qws : kws;
      #pragma unroll
      for (int jp = 0; jp < 2; jp++){
        int dlow = wn * 32 + jp * 16 + l15;          // 0..63
        float bias_lo = bias[cm + dlow];
        float bias_hi = bias[cm + dlow + 64];
        float invf = __expf(-0.14391156831212788f * (float)dlow);
        #pragma unroll
        for (int i = 0; i < 4; i++){
          int srow0 = s0 + wm * 64 + i * 16 + quad * 4;
          #pragma unroll
          for (int r = 0; r < 4; r++){
            float a  = acc[i][jp][r]     + bias_lo;
            float b2 = acc[i][jp + 2][r] + bias_hi;
            float th = (float)(srow0 + r) * invf;
            float sn, cs; __sincosf(th, &sn, &cs);
            size_t ro = base + (size_t)(srow0 + r) * 128;
            dst[ro + dlow]      = f2bf(a * cs - b2 * sn);
            dst[ro + dlow + 64] = f2bf(b2 * cs + a * sn);
          }
        }
      }
    }
  } else {
    int col0 = (int)rowB0;
    #pragma unroll
    for (int j = 0; j < 4; j++){
      int c = col0 + wn * 32 + (j >> 1) * 64 + (j & 1) * 16 + l15;
      float bo_ = bo[c];
      #pragma unroll
      for (int i = 0; i < 4; i++){
        int rg = (int)rowA0 + wm * 64 + i * 16 + quad * 4;
        #pragma unroll
        for (int r = 0; r < 4; r++)
          outf[(size_t)(rg + r) * 2048 + c] = acc[i][j][r] + bo_;
      }
    }
  }
}

// ---------- causal flash attention v9: round-6 config (verified best) + T5 ------
// Rounds 7-9 structure experiments all refuted with mechanism: (r7) exact-160K
// LDS doesn't co-schedule -> 1 block/CU; (r8) launch_bounds(256,4) caps VGPR at
// 64 -> spills; (r9) V-direct from V^T[d][s] is a 64-line gather per load
// (lane-varying d at 4KB stride) -> ~4.3 GB/dispatch through L2 = +90 us. Also:
// grid=512 on 256 CUs caps at 2 blocks/CU regardless of LDS, so the LDS-diet
// lever was vacuous. This round: EXACT round-6 kernel (376.4 us total; LDS-staged
// K+V dbuf 73.75 KB, 2 blocks/CU, lazy softmax, zero-conflict P swizzle, XCD
// swizzle) + T5 s_setprio(1) around the QK and PV MFMA clusters: the CU's two
// INDEPENDENT blocks drift in phase, so MFMA-entering waves get issue priority
// over the other block's softmax/staging waves (m191: +4-7% attn).
__global__ __launch_bounds__(256, 2) void flash(
    const u16* __restrict__ Q, const u16* __restrict__ Km, const u16* __restrict__ VT,
    u16* __restrict__ O)
{
  __shared__ __attribute__((aligned(16))) u16 Ks[2][64 * 128];  // 2x16 KB
  __shared__ __attribute__((aligned(16))) u16 Vs[2][128 * 64];  // 2x16 KB (V^T: [d][kv])
  __shared__ __attribute__((aligned(16))) u16 PL[4 * 16 * 64];  // 8 KB per-wave P
  const float scale = 0.08838834764831845f;   // 1/sqrt(128)

  // XCD-chunked swizzle (id%8 -> XCD, measured r4: FETCH 254->24.6 MB).
  int id = (int)(blockIdx.x + (blockIdx.y << 4));
  int xcd = id & 7;
  int kk_ = id >> 3;                     // 0..63
  int bh = xcd + ((kk_ >> 4) << 3);      // {xcd, xcd+8, xcd+16, xcd+24}
  int pr = kk_ & 15;                     // 0..15
  int tid = threadIdx.x, wave = tid >> 6, lane = tid & 63;
  int quad = lane >> 4, l15 = lane & 15;

  const u16* Qb = Q  + (size_t)bh * 2048 * 128;
  const u16* Kb = Km + (size_t)bh * 2048 * 128;
  const u16* Vb = VT + (size_t)bh * 2048 * 128;   // [d=128][s=2048]
  u16* PW = PL + wave * (16 * 64);

  int krow0 = tid >> 4;
  const u16* gK0 = Kb + (size_t)krow0 * 128 + ((tid & 15) ^ (krow0 & 15)) * 8;
  int vd0 = tid >> 3;
  const u16* gV0 = Vb + (size_t)vd0 * 2048 + ((tid & 7) ^ (vd0 & 7)) * 8;
  int lOff0 = wave * 512;

  for (int phase = 0; phase < 2; phase++){
    int qtile = phase ? (31 - pr) : pr;
    int qw = qtile * 64 + wave * 16;

    short8 qf[4];
    {
      const u16* qr = Qb + (size_t)(qw + l15) * 128 + quad * 8;
      #pragma unroll
      for (int c = 0; c < 4; c++) qf[c] = *(const short8*)(qr + c * 32);
    }

    float mr[4], lrp[4]; f32x4 o[8];
    #pragma unroll
    for (int r = 0; r < 4; r++){ mr[r] = -1e30f; lrp[r] = 0.f; }
    #pragma unroll
    for (int blk = 0; blk < 8; blk++) o[blk] = f32x4{0.f, 0.f, 0.f, 0.f};

    int niter = qtile + 1;

    __syncthreads();   // previous phase's reads of Ks/Vs complete before re-staging
    #pragma unroll
    for (int r = 0; r < 4; r++){
      glds16(gK0 + r * 2048,  Ks[0] + lOff0 + r * 2048);
      glds16(gV0 + r * 65536, Vs[0] + lOff0 + r * 2048);
    }

    for (int it = 0; it < niter; it++){
      int k0 = it * 64;
      int buf = it & 1;
      __syncthreads();   // vmcnt(0)+barrier: buf's tile landed; all waves done w/ buf^1
      if (it + 1 < niter){
        int nb = buf ^ 1;
        #pragma unroll
        for (int r = 0; r < 4; r++){
          glds16(gK0 + (size_t)(k0 + 64) * 128 + r * 2048, Ks[nb] + lOff0 + r * 2048);
          glds16(gV0 + (k0 + 64) + r * 65536,              Vs[nb] + lOff0 + r * 2048);
        }
      }
      const u16* KsB = Ks[buf];
      const u16* VsB = Vs[buf];

      int rel = qw + 15 - k0;
      int smax = rel >> 4; if (smax > 3) smax = 3;
      float sreg[4][4];
      __builtin_amdgcn_s_setprio(1);     // T5: favor this wave's QK MFMA cluster
      #pragma unroll
      for (int t = 0; t < 4; t++){
        if (t <= smax){
          short8 kf[4];
          #pragma unroll
          for (int c = 0; c < 4; c++)
            kf[c] = *(const short8*)(KsB + (t * 16 + l15) * 128 + (((c * 4 + quad) ^ l15) * 8));
          f32x4 a0 = f32x4{0.f, 0.f, 0.f, 0.f};
          f32x4 a1 = f32x4{0.f, 0.f, 0.f, 0.f};
          a0 = __builtin_amdgcn_mfma_f32_16x16x32_bf16(qf[0], kf[0], a0, 0, 0, 0);
          a1 = __builtin_amdgcn_mfma_f32_16x16x32_bf16(qf[1], kf[1], a1, 0, 0, 0);
          a0 = __builtin_amdgcn_mfma_f32_16x16x32_bf16(qf[2], kf[2], a0, 0, 0, 0);
          a1 = __builtin_amdgcn_mfma_f32_16x16x32_bf16(qf[3], kf[3], a1, 0, 0, 0);
          f32x4 a = a0 + a1;
          int kvcol = k0 + t * 16 + l15;
          #pragma unroll
          for (int r = 0; r < 4; r++){
            float v = a[r] * scale;
            int row = qw + quad * 4 + r;
            if (kvcol > row) v = -1e30f;
            sreg[t][r] = v;
          }
        }
      }
      __builtin_amdgcn_s_setprio(0);
      // lane-local per-row tile max (no cross-lane reduce on the common path)
      float lm[4];
      #pragma unroll
      for (int r = 0; r < 4; r++){
        float x = sreg[0][r];
        #pragma unroll
        for (int t = 1; t < 4; t++) if (t <= smax) x = fmaxf(x, sreg[t][r]);
        lm[r] = x;
      }
      // defer-max (T13): single __all over all lanes covers every 16-lane row group
      float g01 = fmaxf(lm[0] - mr[0], lm[1] - mr[1]);
      float g23 = fmaxf(lm[2] - mr[2], lm[3] - mr[3]);
      int noresc = __all(fmaxf(g01, g23) <= 8.0f);
      if (!noresc){
        // rare path: full row-max reduce, rescale o and lane-partial lrp
        float alpha[4];
        #pragma unroll
        for (int r = 0; r < 4; r++){
          float x = lm[r];
          x = fmaxf(x, __shfl_xor(x, 1));
          x = fmaxf(x, __shfl_xor(x, 2));
          x = fmaxf(x, __shfl_xor(x, 4));
          x = fmaxf(x, __shfl_xor(x, 8));
          float mn = fmaxf(mr[r], x);
          alpha[r] = __expf(mr[r] - mn);
          mr[r] = mn;
        }
        #pragma unroll
        for (int r = 0; r < 4; r++) lrp[r] *= alpha[r];
        #pragma unroll
        for (int blk = 0; blk < 8; blk++){
          o[blk][0] *= alpha[0]; o[blk][1] *= alpha[1];
          o[blk][2] *= alpha[2]; o[blk][3] *= alpha[3];
        }
      }
      #pragma unroll
      for (int t = 0; t < 4; t++){
        if (t <= smax){
          int chi = t * 2 + (l15 >> 3);
          #pragma unroll
          for (int r = 0; r < 4; r++){
            float p = __expf(sreg[t][r] - mr[r]);
            lrp[r] += p;
            int row = quad * 4 + r;
            PW[row * 64 + ((chi ^ (row & 7)) << 3) + (l15 & 7)] = f2bf(p);
          }
        }
      }
      if (!(smax & 1)){
        int chi = (smax + 1) * 2 + (l15 >> 3);
        #pragma unroll
        for (int r = 0; r < 4; r++){
          int row = quad * 4 + r;
          PW[row * 64 + ((chi ^ (row & 7)) << 3) + (l15 & 7)] = 0;
        }
      }
      __builtin_amdgcn_s_waitcnt(0xC07F);   // lgkmcnt(0): own-wave P writes visible
      int nch = (smax >> 1) + 1;
      __builtin_amdgcn_s_setprio(1);     // T5: favor this wave's PV MFMA cluster
      #pragma unroll
      for (int c2 = 0; c2 < 2; c2++){
        if (c2 < nch){
          short8 pf = *(const short8*)(PW + l15 * 64 + (((c2 * 4 + quad) ^ (l15 & 7)) << 3));
          #pragma unroll
          for (int blk = 0; blk < 8; blk++){
            int d = blk * 16 + l15;
            short8 vf = *(const short8*)(VsB + d * 64 + (((c2 * 4 + quad) ^ (l15 & 7)) * 8));
            o[blk] = __builtin_amdgcn_mfma_f32_16x16x32_bf16(pf, vf, o[blk], 0, 0, 0);
          }
        }
      }
      __builtin_amdgcn_s_setprio(0);
    }

    // phase epilogue: ONE lane-group reduce of the lane-partial denominators
    int b = bh >> 4, h = bh & 15;
    float inv[4];
    #pragma unroll
    for (int r = 0; r < 4; r++){
      float sv = lrp[r];
      sv += __shfl_xor(sv, 1); sv += __shfl_xor(sv, 2);
      sv += __shfl_xor(sv, 4); sv += __shfl_xor(sv, 8);
      inv[r] = 1.0f / sv;
    }
    #pragma unroll
    for (int blk = 0; blk < 8; blk++){
      int d = h * 128 + blk * 16 + l15;
      #pragma unroll
      for (int r = 0; r < 4; r++){
        int srow = qw + quad * 4 + r;
        O[((size_t)(b * 2048 + srow)) * 2048 + d] = f2bf(o[blk][r] * inv[r]);
      }
    }
  }
}

// ---------- launcher ----------
extern "C" void kernel_launch(void* const* d_in, const int* in_sizes, int n_in,
                              void* d_out, int out_size, void* d_ws, size_t ws_size,
                              hipStream_t stream)
{
  const float* x  = (const float*)d_in[0];
  const float* Wq = (const float*)d_in[2];
  const float* bq = (const float*)d_in[3];
  const float* Wk = (const float*)d_in[4];
  const float* bk = (const float*)d_in[5];
  const float* Wv = (const float*)d_in[6];
  const float* bv = (const float*)d_in[7];
  const float* Wo = (const float*)d_in[8];
  const float* bo = (const float*)d_in[9];
  float* out = (float*)d_out;

  char* ws = (char*)d_ws;
  u16* xb   = (u16*)(ws);                    // [4096][2048]
  u16* wcat = (u16*)(ws + 16777216);         // [6144][2048] Wq|Wk|Wv
  u16* wob  = (u16*)(ws + 41943040);         // [2048][2048]
  u16* qws  = (u16*)(ws + 50331648);         // [32][2048][128]
  u16* kws  = (u16*)(ws + 67108864);
  u16* vws  = (u16*)(ws + 83886080);         // [32][128][2048] V^T
  u16* attn = (u16*)(ws + 100663296);        // [4096][2048]

  cvt_all<<<24576, 256, 0, stream>>>(x, Wq, Wk, Wv, Wo, xb, wcat);

  gemm_bt<<<dim3(48, 32), 256, 0, stream>>>(xb, wcat, 0, qws, kws, vws,
                                            bq, bk, bv, nullptr, nullptr);
  flash<<<dim3(16, 32), 256, 0, stream>>>(qws, kws, vws, attn);
  gemm_bt<<<dim3(16, 32), 256, 0, stream>>>(attn, wob, 1, nullptr, nullptr, nullptr,
                                            nullptr, nullptr, nullptr, out, bo);
}